// Round 3
// baseline (584.418 us; speedup 1.0000x reference)
//
#include <hip/hip_runtime.h>

typedef _Float16 half8 __attribute__((ext_vector_type(8)));
typedef _Float16 half2t __attribute__((ext_vector_type(2)));
typedef float float4t __attribute__((ext_vector_type(4)));
typedef float float2t __attribute__((ext_vector_type(2)));

#define BATCH 32
#define CIN 64
#define HIN 128
#define WIN 128
#define COUT 128
#define HOUT 126
#define WOUT 126
#define HP 63
#define WP 63
#define NGROUPS 16
#define CPG 8
#define EPSV 1e-5f

#define XS_COLS 130
#define XS_CSTR 72   // cin stride in fp16 elems = 144B (16B multiple -> aligned ds_read_b128)

// wT[pos][cout][cin] fp16, pos = kh*3+kw ; also zeroes stats
__global__ __launch_bounds__(256) void wt_kernel(const float* __restrict__ w,
                                                 _Float16* __restrict__ wT,
                                                 float* __restrict__ stats) {
    int idx = blockIdx.x * 256 + threadIdx.x;
    if (idx < BATCH * NGROUPS * 2) stats[idx] = 0.f;
    if (idx >= 9 * COUT * CIN) return;
    int cin = idx & 63;
    int t = idx >> 6;
    int cout = t & 127;
    int pos = t >> 7;
    wT[idx] = (_Float16)w[(cout * CIN + cin) * 9 + pos];
}

// grid: x = oy (126), y = b (32). Block: 4 waves; wave -> 64 couts x 64 pixels.
__global__ __launch_bounds__(256, 2) void conv_mfma_kernel(
    const float* __restrict__ x, const _Float16* __restrict__ wT,
    const float* __restrict__ bias, float* __restrict__ y,
    float* __restrict__ stats)
{
    __shared__ __align__(16) _Float16 xs[3 * XS_COLS * XS_CSTR];

    const int tid = threadIdx.x;
    const int oy = blockIdx.x;
    const int b  = blockIdx.y;

    // ---- stage xs[r][col][cin] = fp16(x[b][cin][oy+r][col]), once per block ----
    {
        const int cp  = tid & 31;        // cin pair -> cins {2cp, 2cp+1}
        const int seg = tid >> 5;        // col segment of 16
        const int c0s = 2 * cp;
        const float* xb = x + (size_t)b * CIN * (HIN * WIN);
        for (int i = 0; i < 12; i++) {
            int r = i >> 2;
            int col4 = seg * 16 + (i & 3) * 4;
            const float* p0 = xb + ((size_t)c0s * HIN + (oy + r)) * WIN + col4;
            const float* p1 = p0 + (size_t)HIN * WIN;
            float4t va = *(const float4t*)p0;
            float4t vb = *(const float4t*)p1;
            _Float16* dst = &xs[(r * XS_COLS + col4) * XS_CSTR + c0s];
#pragma unroll
            for (int j = 0; j < 4; j++) {
                half2t hv = { (_Float16)va[j], (_Float16)vb[j] };
                *(half2t*)(dst + j * XS_CSTR) = hv;
            }
        }
        // zero pad cols 128,129
        if (tid < 192) {
            int cpz = tid & 31;
            int colx = (tid >> 5) & 1;
            int r = tid >> 6;
            half2t z = { (_Float16)0.f, (_Float16)0.f };
            *(half2t*)&xs[(r * XS_COLS + 128 + colx) * XS_CSTR + 2 * cpz] = z;
        }
    }
    __syncthreads();

    const int lane = tid & 63;
    const int wv   = tid >> 6;
    const int m    = lane & 15;
    const int q    = lane >> 4;
    const int c0   = (wv >> 1) * 64;    // cout base for this wave
    const int px0  = (wv & 1) * 64;     // pixel base for this wave

    float4t acc[4][4];
#pragma unroll
    for (int s = 0; s < 4; s++)
#pragma unroll
        for (int n = 0; n < 4; n++)
            acc[s][n] = (float4t){0.f, 0.f, 0.f, 0.f};

    half8 a_cur[4], a_nxt[4];
    {
        const _Float16* ab = wT + (size_t)(c0 + m) * CIN + q * 8;
#pragma unroll
        for (int s = 0; s < 4; s++) a_cur[s] = *(const half8*)(ab + s * 16 * CIN);
    }

#pragma unroll
    for (int kk = 0; kk < 18; kk++) {
        const int pos = kk >> 1, ch = kk & 1;
        const int kh = pos / 3, kw = pos % 3;

        if (kk < 17) {
            const int nk = kk + 1, npos = nk >> 1, nch = nk & 1;
            const _Float16* ab = wT + ((size_t)npos * COUT + c0 + m) * CIN + q * 8 + nch * 32;
#pragma unroll
            for (int s = 0; s < 4; s++) a_nxt[s] = *(const half8*)(ab + s * 16 * CIN);
        }

        const _Float16* bb = &xs[(kh * XS_COLS + px0 + m + kw) * XS_CSTR + q * 8 + ch * 32];
#pragma unroll
        for (int n = 0; n < 4; n++) {
            half8 bf = *(const half8*)(bb + n * 16 * XS_CSTR);
#pragma unroll
            for (int s = 0; s < 4; s++)
                acc[s][n] = __builtin_amdgcn_mfma_f32_16x16x32_f16(a_cur[s], bf, acc[s][n], 0, 0, 0);
        }
#pragma unroll
        for (int s = 0; s < 4; s++) a_cur[s] = a_nxt[s];
    }

    // ---- epilogue: bias, store y (fp32), per-group stats ----
    float sv[4] = {0.f, 0.f, 0.f, 0.f}, ssv[4] = {0.f, 0.f, 0.f, 0.f};
    float bval[4][4];
#pragma unroll
    for (int s = 0; s < 4; s++)
#pragma unroll
        for (int reg = 0; reg < 4; reg++)
            bval[s][reg] = bias[c0 + s * 16 + q * 4 + reg];

#pragma unroll
    for (int s = 0; s < 4; s++) {
#pragma unroll
        for (int n = 0; n < 4; n++) {
            int pix = px0 + n * 16 + m;
            bool valid = pix < WOUT;
            float* yp = y + (((size_t)b * COUT + c0 + s * 16 + q * 4) * HOUT + oy) * WOUT + pix;
#pragma unroll
            for (int reg = 0; reg < 4; reg++) {
                float v = acc[s][n][reg] + bval[s][reg];
                if (valid) {
                    yp[(size_t)reg * HOUT * WOUT] = v;
                    sv[s] += v;
                    ssv[s] += v * v;
                }
            }
        }
    }
    // lanes 0..31 (q=0,1) -> group c0/8 + s*2; lanes 32..63 -> +1
#pragma unroll
    for (int s = 0; s < 4; s++) {
        float a = sv[s], c = ssv[s];
        for (int off = 16; off; off >>= 1) {
            a += __shfl_down(a, off, 32);
            c += __shfl_down(c, off, 32);
        }
        if ((lane & 31) == 0) {
            int g = (c0 >> 3) + s * 2 + (lane >> 5);
            atomicAdd(&stats[(b * NGROUPS + g) * 2 + 0], a);
            atomicAdd(&stats[(b * NGROUPS + g) * 2 + 1], c);
        }
    }
}

// thread -> (b, c, hp, wp-pair): 2 pooled outputs, float4 loads
__global__ __launch_bounds__(256) void norm_pool_kernel(
    const float* __restrict__ y, const float* __restrict__ stats,
    const float* __restrict__ gnw, const float* __restrict__ gnb,
    const float* __restrict__ scale, float* __restrict__ out)
{
    int idx = blockIdx.x * 256 + threadIdx.x;   // exact: 32*128*63*32 threads
    int wp2 = idx & 31;
    int t = idx >> 5;
    int hp = t % HP; t /= HP;
    int c = t & 127;
    int b = t >> 7;
    int g = c >> 3;

    const float N = (float)(CPG * HOUT * WOUT);
    float sum   = stats[(b * NGROUPS + g) * 2 + 0];
    float sumsq = stats[(b * NGROUPS + g) * 2 + 1];
    float mean = sum / N;
    float var  = sumsq / N - mean * mean;
    float rstd = rsqrtf(var + EPSV);

    float A  = gnw[c] * rstd * scale[c];
    float B2 = (gnb[c] - mean * gnw[c] * rstd) * scale[c];

    const float* yp = y + (((size_t)b * COUT + c) * HOUT + hp * 2) * WOUT + wp2 * 4;
    float4t r0 = *(const float4t*)yp;                      // row 2hp: 16B-aligned
    float2t r1a = *(const float2t*)(yp + WOUT);            // row 2hp+1: 8B-aligned
    float2t r1b = *(const float2t*)(yp + WOUT + 2);

    float v0 = fmaf(r0.x, A, B2), v1 = fmaf(r0.y, A, B2);
    float v2 = fmaf(r0.z, A, B2), v3 = fmaf(r0.w, A, B2);
    float u0 = fmaf(r1a.x, A, B2), u1 = fmaf(r1a.y, A, B2);
    float u2 = fmaf(r1b.x, A, B2), u3 = fmaf(r1b.y, A, B2);

    float p0 = fmaxf(fmaxf(v0, v1), fmaxf(u0, u1));
    float p1 = fmaxf(fmaxf(v2, v3), fmaxf(u2, u3));
    p0 = fminf(fmaxf(p0, 0.0f), 1.0f);
    p1 = fminf(fmaxf(p1, 0.0f), 1.0f);

    int wp = wp2 * 2;
    size_t o = (((size_t)b * COUT + c) * HP + hp) * WP + wp;
    out[o] = p0;
    if (wp + 1 < WP) out[o + 1] = p1;
}

extern "C" void kernel_launch(void* const* d_in, const int* in_sizes, int n_in,
                              void* d_out, int out_size, void* d_ws, size_t ws_size,
                              hipStream_t stream) {
    const float* x      = (const float*)d_in[0];
    const float* conv_w = (const float*)d_in[1];
    const float* conv_b = (const float*)d_in[2];
    const float* gnw    = (const float*)d_in[3];
    const float* gnb    = (const float*)d_in[4];
    const float* scale  = (const float*)d_in[5];
    float* out = (float*)d_out;

    const size_t y_bytes = (size_t)BATCH * COUT * HOUT * WOUT * sizeof(float);
    float* y     = (float*)d_ws;
    float* stats = (float*)((char*)d_ws + y_bytes);
    _Float16* wT = (_Float16*)((char*)d_ws + y_bytes + 4096);

    wt_kernel<<<(9 * COUT * CIN + 255) / 256, 256, 0, stream>>>(conv_w, wT, stats);

    dim3 grid(HOUT, BATCH);
    conv_mfma_kernel<<<grid, 256, 0, stream>>>(x, wT, conv_b, y, stats);

    const int total = BATCH * COUT * HP * 32;
    norm_pool_kernel<<<total / 256, 256, 0, stream>>>(y, stats, gnw, gnb, scale, out);
}